// Round 1
// baseline (584.449 us; speedup 1.0000x reference)
//
#include <hip/hip_runtime.h>
#include <math.h>

#define NF 1000
#define NC 1000
#define NB 16384
#define ALPHA_C 0.5f
#define BETA_C 0.003f
#define GAMMA_C 0.001f

__device__ __forceinline__ float wave_reduce_sum(float v) {
#pragma unroll
    for (int off = 32; off > 0; off >>= 1) v += __shfl_down(v, off, 64);
    return v;
}
__device__ __forceinline__ float wave_reduce_max(float v) {
#pragma unroll
    for (int off = 32; off > 0; off >>= 1) v = fmaxf(v, __shfl_down(v, off, 64));
    return v;
}

// One block (256 threads) per batch row.
// Computes: CE contribution, ||x - c_y||^2 (-> center_loss sum and S2[class]),
// counts[class], and atomic segment-sum sum_x[class, f].
__global__ __launch_bounds__(256) void row_pass(
    const float* __restrict__ x, const int* __restrict__ y,
    const float* __restrict__ centers,
    float* __restrict__ sum_x, float* __restrict__ counts,
    float* __restrict__ S2, float* __restrict__ scalars) {
    __shared__ float sbuf[8];
    const int b = blockIdx.x;
    const int t = threadIdx.x;
    const float* xrow = x + (size_t)b * NF;
    const int cls = y[b];
    const float* crow = centers + (size_t)cls * NF;

    float xv[4];
    float lmax = -INFINITY;
#pragma unroll
    for (int i = 0; i < 4; i++) {
        int f = t + i * 256;
        xv[i] = (f < NF) ? xrow[f] : -INFINITY;
        lmax = fmaxf(lmax, xv[i]);
    }
    float wmax = wave_reduce_max(lmax);
    const int wid = t >> 6, lane = t & 63;
    if (lane == 0) sbuf[wid] = wmax;
    __syncthreads();
    const float rmax = fmaxf(fmaxf(sbuf[0], sbuf[1]), fmaxf(sbuf[2], sbuf[3]));

    float lsum = 0.f, ld2 = 0.f;
#pragma unroll
    for (int i = 0; i < 4; i++) {
        int f = t + i * 256;
        if (f < NF) {
            lsum += expf(xv[i] - rmax);
            float d = xv[i] - crow[f];
            ld2 += d * d;
            atomicAdd(&sum_x[(size_t)cls * NF + f], xv[i]);
        }
    }
    float wsum = wave_reduce_sum(lsum);
    float wd2 = wave_reduce_sum(ld2);
    __syncthreads();  // sbuf reuse
    if (lane == 0) { sbuf[wid] = wsum; sbuf[4 + wid] = wd2; }
    __syncthreads();
    if (t == 0) {
        float sumexp = sbuf[0] + sbuf[1] + sbuf[2] + sbuf[3];
        float d2 = sbuf[4] + sbuf[5] + sbuf[6] + sbuf[7];
        float xy = xrow[cls];                       // x[b, y[b]] (C == F)
        float ce = -(xy - rmax - logf(sumexp));     // -logp[b, y[b]]
        atomicAdd(&scalars[0], ce);
        atomicAdd(&scalars[1], d2);
        atomicAdd(&S2[cls], d2);
        atomicAdd(&counts[cls], 1.0f);
    }
}

// One block per class: new_centers, sum of ||new_c||^2, intra-loss terms.
__global__ __launch_bounds__(256) void class_pass(
    const float* __restrict__ centers, const float* __restrict__ sum_x,
    const float* __restrict__ counts, const float* __restrict__ S2,
    float* __restrict__ new_centers, float* __restrict__ scalars) {
    __shared__ float sbuf[8];
    const int c = blockIdx.x, t = threadIdx.x;
    const float n = counts[c];
    const float inv = (n > 0.f) ? 1.f / n : 0.f;
    float lsq = 0.f, lmd2 = 0.f;
    for (int f = t; f < NF; f += 256) {
        float cen = centers[(size_t)c * NF + f];
        float md = (n > 0.f) ? (sum_x[(size_t)c * NF + f] * inv - cen) : 0.f;
        float nc = cen + ALPHA_C * md;
        new_centers[(size_t)c * NF + f] = nc;
        lsq += nc * nc;
        lmd2 += md * md;
    }
    float w1 = wave_reduce_sum(lsq), w2 = wave_reduce_sum(lmd2);
    const int wid = t >> 6, lane = t & 63;
    if (lane == 0) { sbuf[wid] = w1; sbuf[4 + wid] = w2; }
    __syncthreads();
    if (t == 0) {
        float sq = sbuf[0] + sbuf[1] + sbuf[2] + sbuf[3];
        float md2 = sbuf[4] + sbuf[5] + sbuf[6] + sbuf[7];
        atomicAdd(&scalars[2], sq);
        // per-class intra mean: S2/n - alpha*(2-alpha)*||md||^2   (0 if empty)
        float intra = (n > 0.f) ? (S2[c] * inv - ALPHA_C * (2.f - ALPHA_C) * md2) : 0.f;
        atomicAdd(&scalars[3], intra);
    }
}

// s[f] = sum_c new_centers[c,f]; accumulate ||s||^2.
__global__ __launch_bounds__(256) void col_sum(
    const float* __restrict__ new_centers, float* __restrict__ scalars) {
    __shared__ float sbuf[4];
    const int f = blockIdx.x * 256 + threadIdx.x;
    float s = 0.f;
    if (f < NF) {
        for (int c = 0; c < NC; c++) s += new_centers[(size_t)c * NF + f];
    }
    float v = (f < NF) ? s * s : 0.f;
    float w = wave_reduce_sum(v);
    const int wid = threadIdx.x >> 6, lane = threadIdx.x & 63;
    if (lane == 0) sbuf[wid] = w;
    __syncthreads();
    if (threadIdx.x == 0) atomicAdd(&scalars[4], sbuf[0] + sbuf[1] + sbuf[2] + sbuf[3]);
}

__global__ void finalize(const float* __restrict__ scalars, float* __restrict__ out) {
    float ce = scalars[0] / (float)NB;
    float cl = scalars[1] / (float)NB;
    float num_pairs = (float)NC * (float)(NC - 1) * 0.5f;
    float inter = ((float)NC * scalars[2] - scalars[4]) / num_pairs;
    float intra = scalars[3] / (float)NC;
    out[0] = ce + BETA_C * cl + GAMMA_C * inter + GAMMA_C * intra;
}

extern "C" void kernel_launch(void* const* d_in, const int* in_sizes, int n_in,
                              void* d_out, int out_size, void* d_ws, size_t ws_size,
                              hipStream_t stream) {
    const float* x = (const float*)d_in[0];
    const int* y = (const int*)d_in[1];
    const float* centers = (const float*)d_in[2];
    float* out = (float*)d_out;

    char* ws = (char*)d_ws;
    float* sum_x       = (float*)(ws);                 // 4,000,000 B
    float* new_centers = (float*)(ws + 4000000);       // 4,000,000 B
    float* counts      = (float*)(ws + 8000000);       // 4,000 B
    float* S2          = (float*)(ws + 8004000);       // 4,000 B
    float* scalars     = (float*)(ws + 8008000);       // 32 B

    hipMemsetAsync(sum_x, 0, 4000000, stream);
    hipMemsetAsync(counts, 0, 8032, stream);  // counts + S2 + scalars

    row_pass<<<NB, 256, 0, stream>>>(x, y, centers, sum_x, counts, S2, scalars);
    class_pass<<<NC, 256, 0, stream>>>(centers, sum_x, counts, S2, new_centers, scalars);
    col_sum<<<(NF + 255) / 256, 256, 0, stream>>>(new_centers, scalars);
    finalize<<<1, 1, 0, stream>>>(scalars, out);
}

// Round 3
// 181.605 us; speedup vs baseline: 3.2182x; 3.2182x over previous
//
#include <hip/hip_runtime.h>
#include <math.h>

#define NF 1000
#define NC 1000
#define NB 16384
#define NV 250          // NF/4 float4s per row
#define ALPHA_C 0.5f
#define BETA_C 0.003f
#define GAMMA_C 0.001f

__device__ __forceinline__ float wave_sum(float v) {
#pragma unroll
    for (int off = 32; off > 0; off >>= 1) v += __shfl_xor(v, off, 64);
    return v;
}
__device__ __forceinline__ float wave_max(float v) {
#pragma unroll
    for (int off = 32; off > 0; off >>= 1) v = fmaxf(v, __shfl_xor(v, off, 64));
    return v;
}

// One wave per row (4 rows per 256-thread block). Computes ce[b], d2[b],
// and the class histogram. Wave-level reductions only -- no LDS, no barriers.
__global__ __launch_bounds__(256) void row_pass(
    const float* __restrict__ x, const int* __restrict__ y,
    const float* __restrict__ centers,
    float* __restrict__ ce, float* __restrict__ d2, int* __restrict__ counts) {
    const int wid = threadIdx.x >> 6, lane = threadIdx.x & 63;
    const int b = blockIdx.x * 4 + wid;
    const int cls = y[b];
    const float4* xrow = (const float4*)(x + (size_t)b * NF);
    const float4* crow = (const float4*)(centers + (size_t)cls * NF);

    float4 xv[4];
    float lmax = -INFINITY;
#pragma unroll
    for (int i = 0; i < 4; i++) {
        int idx = lane + i * 64;
        if (idx < NV) {
            xv[i] = xrow[idx];
            lmax = fmaxf(fmaxf(fmaxf(lmax, xv[i].x), fmaxf(xv[i].y, xv[i].z)), xv[i].w);
        } else {
            xv[i] = make_float4(-INFINITY, -INFINITY, -INFINITY, -INFINITY);
        }
    }
    const float rmax = wave_max(lmax);

    float lsum = 0.f, ld2 = 0.f;
#pragma unroll
    for (int i = 0; i < 4; i++) {
        int idx = lane + i * 64;
        // expf(-INF - rmax) == 0, so inactive slots contribute nothing to lsum
        lsum += expf(xv[i].x - rmax) + expf(xv[i].y - rmax) +
                expf(xv[i].z - rmax) + expf(xv[i].w - rmax);
        if (idx < NV) {
            float4 cv = crow[idx];
            float dx = xv[i].x - cv.x, dy = xv[i].y - cv.y;
            float dz = xv[i].z - cv.z, dw = xv[i].w - cv.w;
            ld2 += dx * dx + dy * dy + dz * dz + dw * dw;
        }
    }
    const float sumexp = wave_sum(lsum);
    const float rd2 = wave_sum(ld2);
    if (lane == 0) {
        float xy = x[(size_t)b * NF + cls];
        ce[b] = -(xy - rmax - logf(sumexp));
        d2[b] = rd2;
        atomicAdd(&counts[cls], 1);
    }
}

// Single-block Hillis-Steele scan: offsets[c] = exclusive prefix of counts.
__global__ __launch_bounds__(1024) void scan_counts(
    const int* __restrict__ counts, int* __restrict__ offsets) {
    __shared__ int s[1024];
    const int t = threadIdx.x;
    const int v = (t < NC) ? counts[t] : 0;
    s[t] = v;
    __syncthreads();
    for (int d = 1; d < 1024; d <<= 1) {
        int add = (t >= d) ? s[t - d] : 0;
        __syncthreads();
        s[t] += add;
        __syncthreads();
    }
    if (t < NC) offsets[t] = s[t] - v;
}

__global__ __launch_bounds__(256) void scatter_rows(
    const int* __restrict__ y, const int* __restrict__ offsets,
    int* __restrict__ cursor, int* __restrict__ rids) {
    const int b = blockIdx.x * 256 + threadIdx.x;
    if (b < NB) {
        int cls = y[b];
        int p = atomicAdd(&cursor[cls], 1);
        rids[offsets[cls] + p] = b;
    }
}

// One block per class. Registers hold sum_x (float4/thread). Gathers this
// class's rows of x (L3-resident after row_pass), ce[b], d2[b].
__global__ __launch_bounds__(256) void class_pass(
    const float* __restrict__ x, const float* __restrict__ centers,
    const int* __restrict__ counts, const int* __restrict__ offsets,
    const int* __restrict__ rids,
    const float* __restrict__ ce, const float* __restrict__ d2,
    float* __restrict__ new_centers, float* __restrict__ scalars) {
    __shared__ float sb[16];
    const int c = blockIdx.x, t = threadIdx.x;
    const int n = counts[c], off = offsets[c];

    float4 s0 = make_float4(0, 0, 0, 0), s1 = make_float4(0, 0, 0, 0);
    int i = 0;
    for (; i + 1 < n; i += 2) {
        int b0 = rids[off + i], b1 = rids[off + i + 1];
        if (t < NV) {
            float4 v0 = ((const float4*)(x + (size_t)b0 * NF))[t];
            float4 v1 = ((const float4*)(x + (size_t)b1 * NF))[t];
            s0.x += v0.x; s0.y += v0.y; s0.z += v0.z; s0.w += v0.w;
            s1.x += v1.x; s1.y += v1.y; s1.z += v1.z; s1.w += v1.w;
        }
    }
    if (i < n) {
        int b0 = rids[off + i];
        if (t < NV) {
            float4 v0 = ((const float4*)(x + (size_t)b0 * NF))[t];
            s0.x += v0.x; s0.y += v0.y; s0.z += v0.z; s0.w += v0.w;
        }
    }
    s0.x += s1.x; s0.y += s1.y; s0.z += s1.z; s0.w += s1.w;

    float lce = 0.f, ld2 = 0.f;
    for (int j = t; j < n; j += 256) {
        int b = rids[off + j];
        lce += ce[b];
        ld2 += d2[b];
    }

    const float inv = (n > 0) ? 1.f / (float)n : 0.f;
    float lsq = 0.f, lmd2 = 0.f;
    if (t < NV) {
        float4 cv = ((const float4*)(centers + (size_t)c * NF))[t];
        float4 md, nc;
        md.x = (n > 0) ? (s0.x * inv - cv.x) : 0.f;
        md.y = (n > 0) ? (s0.y * inv - cv.y) : 0.f;
        md.z = (n > 0) ? (s0.z * inv - cv.z) : 0.f;
        md.w = (n > 0) ? (s0.w * inv - cv.w) : 0.f;
        nc.x = cv.x + ALPHA_C * md.x; nc.y = cv.y + ALPHA_C * md.y;
        nc.z = cv.z + ALPHA_C * md.z; nc.w = cv.w + ALPHA_C * md.w;
        ((float4*)(new_centers + (size_t)c * NF))[t] = nc;
        lsq = nc.x * nc.x + nc.y * nc.y + nc.z * nc.z + nc.w * nc.w;
        lmd2 = md.x * md.x + md.y * md.y + md.z * md.z + md.w * md.w;
    }

    float w0 = wave_sum(lsq), w1 = wave_sum(lmd2), w2 = wave_sum(lce), w3 = wave_sum(ld2);
    const int wid = t >> 6, lane = t & 63;
    if (lane == 0) { sb[wid] = w0; sb[4 + wid] = w1; sb[8 + wid] = w2; sb[12 + wid] = w3; }
    __syncthreads();
    if (t == 0) {
        float sq  = sb[0] + sb[1] + sb[2] + sb[3];
        float md2 = sb[4] + sb[5] + sb[6] + sb[7];
        float ces = sb[8] + sb[9] + sb[10] + sb[11];
        float s2  = sb[12] + sb[13] + sb[14] + sb[15];
        atomicAdd(&scalars[0], ces);
        atomicAdd(&scalars[1], s2);
        atomicAdd(&scalars[2], sq);
        // per-class intra mean: S2/n - alpha*(2-alpha)*||md||^2
        float intra = (n > 0) ? (s2 * inv - ALPHA_C * (2.f - ALPHA_C) * md2) : 0.f;
        atomicAdd(&scalars[3], intra);
    }
}

// Partial column sums: grid (4, 8); blockIdx.y picks a 125-class chunk.
__global__ __launch_bounds__(256) void col_partial(
    const float* __restrict__ new_centers, float* __restrict__ s) {
    const int f = blockIdx.x * 256 + threadIdx.x;
    if (f >= NF) return;
    const int c0 = blockIdx.y * 125;
    float acc = 0.f;
    for (int c = c0; c < c0 + 125; c++) acc += new_centers[(size_t)c * NF + f];
    atomicAdd(&s[f], acc);
}

__global__ __launch_bounds__(1024) void finalize(
    const float* __restrict__ s, const float* __restrict__ scalars,
    float* __restrict__ out) {
    __shared__ float sb[16];
    const int t = threadIdx.x;
    float v = (t < NF) ? s[t] * s[t] : 0.f;
    float w = wave_sum(v);
    if ((t & 63) == 0) sb[t >> 6] = w;
    __syncthreads();
    if (t == 0) {
        float ssq = 0.f;
        for (int k = 0; k < 16; k++) ssq += sb[k];
        float cem = scalars[0] / (float)NB;
        float cl = scalars[1] / (float)NB;
        float num_pairs = (float)NC * (float)(NC - 1) * 0.5f;
        float inter = ((float)NC * scalars[2] - ssq) / num_pairs;
        float intra = scalars[3] / (float)NC;
        out[0] = cem + BETA_C * cl + GAMMA_C * inter + GAMMA_C * intra;
    }
}

extern "C" void kernel_launch(void* const* d_in, const int* in_sizes, int n_in,
                              void* d_out, int out_size, void* d_ws, size_t ws_size,
                              hipStream_t stream) {
    const float* x = (const float*)d_in[0];
    const int* y = (const int*)d_in[1];
    const float* centers = (const float*)d_in[2];
    float* out = (float*)d_out;

    char* ws = (char*)d_ws;
    float* ce      = (float*)(ws);                    // 65536 B
    float* d2      = (float*)(ws + 65536);            // 65536 B
    int* rids      = (int*)(ws + 131072);             // 65536 B
    int* offsets   = (int*)(ws + 196608);             // 4096 B
    // --- zeroed region (one memset) ---
    int* counts    = (int*)(ws + 200704);             // 4096 B
    int* cursor    = (int*)(ws + 204800);             // 4096 B
    float* s       = (float*)(ws + 208896);           // 4096 B
    float* scalars = (float*)(ws + 212992);           // 64 B
    // --- end zeroed region (12352 B) ---
    float* new_centers = (float*)(ws + 213248);       // 4,000,000 B

    hipMemsetAsync(counts, 0, 12352, stream);

    row_pass<<<NB / 4, 256, 0, stream>>>(x, y, centers, ce, d2, counts);
    scan_counts<<<1, 1024, 0, stream>>>(counts, offsets);
    scatter_rows<<<(NB + 255) / 256, 256, 0, stream>>>(y, offsets, cursor, rids);
    class_pass<<<NC, 256, 0, stream>>>(x, centers, counts, offsets, rids,
                                       ce, d2, new_centers, scalars);
    dim3 cgrid(4, 8);
    col_partial<<<cgrid, 256, 0, stream>>>(new_centers, s);
    finalize<<<1, 1024, 0, stream>>>(s, scalars, out);
}